// Round 6
// baseline (410.507 us; speedup 1.0000x reference)
//
#include <hip/hip_runtime.h>
#include <cstdint>
#include <cstddef>

typedef unsigned short u16;
typedef unsigned int u32;
typedef __bf16 bf16x8 __attribute__((ext_vector_type(8)));
typedef float f32x4 __attribute__((ext_vector_type(4)));

#define SL 2048            // sequence length
#define NCH 8192           // B(16) * BIDIR(2) * N_OUT(256)
#define SEGS 64

// out buffer element offsets (f32 output)
#define OFF_C2S 16777216
#define OFF_C1F 33554432
#define OFF_C2F 33562624
#define OFF_DF  33570816

__device__ __forceinline__ u16 f2bf(float f) {
  union { float f; u32 i; } v; v.f = f;
  u32 x = v.i;
  return (u16)((x + 0x7fffu + ((x >> 16) & 1u)) >> 16);
}
// pack two f32 -> two bf16 (RNE), 1 VALU op
__device__ __forceinline__ u32 cvtpk(float lo, float hi) {
  u32 r;
  asm("v_cvt_pk_bf16_f32 %0, %1, %2" : "=v"(r) : "v"(lo), "v"(hi));
  return r;
}
__device__ __forceinline__ float sigmoidf(float v) {
  return 1.f / (1.f + __expf(-v));
}

// -------------------------------------------------------------------------
// Convert x (f32 [t][b][256]) -> xb (bf16, layout [ot][kb(32)][b(16)][8]).
__global__ __launch_bounds__(256) void xconv_kernel(
    const float* __restrict__ x, u16* __restrict__ xb) {
  int t8 = blockIdx.x * 256 + threadIdx.x;    // < 1,048,576
  int b  = t8 & 15;
  int kb = (t8 >> 4) & 31;
  int ot = t8 >> 9;
  const float* src = x + (((size_t)(ot * 16 + b)) << 8) + kb * 8;
  f32x4 a = *(const f32x4*)src;
  f32x4 c = *(const f32x4*)(src + 4);
  union { bf16x8 v; u32 u[4]; } h;
  h.u[0] = cvtpk(a[0], a[1]);
  h.u[1] = cvtpk(a[2], a[3]);
  h.u[2] = cvtpk(c[0], c[1]);
  h.u[3] = cvtpk(c[2], c[3]);
  *(bf16x8*)(xb + ((size_t)ot << 12) + kb * 128 + b * 8) = h.v;
}

// -------------------------------------------------------------------------
// Repack weight_in (f32, 256 x 3072) into MFMA-fragment-ordered bf16 Wt.
// Fragment f = p*256 + cg*8 + kt*2 + h holds at [lane][kk8]:
//   ch2 = cg*16 + (lane&15), kk = (kt*8 + h*4 + (lane>>4))*8 + kk8.
__global__ __launch_bounds__(256) void repack_kernel(
    const float* __restrict__ W, u16* __restrict__ Wt) {
  int idx = blockIdx.x * 256 + threadIdx.x;   // < 256*3072 = 786432
  int col = idx % 3072;
  int kk  = idx / 3072;
  float w = W[idx];                            // coalesced
  int d    = (col >= 1536) ? 1 : 0;
  int col2 = col - d * 1536;
  int n = col2 / 6;
  int p = col2 - n * 6;
  if (p >= 5) return;                          // selfloop plane unused
  int ch2 = d * 256 + n;
  int cg = ch2 >> 4, l15 = ch2 & 15;
  int kk8 = kk & 7, q = kk >> 3;
  int l4 = q & 3, h = (q >> 2) & 1, kt = q >> 3;
  size_t dst = ((size_t)(p * 256 + cg * 8 + kt * 2 + h)) * 512 +
               (l4 * 16 + l15) * 8 + kk8;
  Wt[dst] = f2bf(w);
}

// -------------------------------------------------------------------------
// X2B precompute: u2 (plane 1) at flipped t = s*32+31 for every segment.
// Block = (s, bc); wave wc covers 16 ch2 x 16 b at one timestep, K=256.
// Layout X2B[s][ch2(512)][b(16)] f32.
__global__ __launch_bounds__(256) void x2seg_kernel(
    const u16* __restrict__ xb, const u16* __restrict__ Wt,
    float* __restrict__ X2B) {
  const int tid = threadIdx.x;
  const int lane = tid & 63;
  const int wc = tid >> 6;
  const int l15 = lane & 15, l4 = lane >> 4;
  const int s = blockIdx.x;          // 0..63
  const int bc = blockIdx.y;         // 0..7
  const int dir = bc >> 2;
  const int ch2 = bc * 64 + wc * 16 + l15;
  const int fb0 = (bc * 4 + wc) * 8;
  int tf = s * 32 + 31;
  int ot = dir ? (SL - 1 - tf) : tf;
  const u16* ab = xb + ((size_t)ot << 12) + l4 * 128 + l15 * 8;
  f32x4 acc = (f32x4){0.f, 0.f, 0.f, 0.f};
#pragma unroll
  for (int kt = 0; kt < 4; ++kt)
#pragma unroll
    for (int h = 0; h < 2; ++h) {
      const int kb4 = (kt * 8 + h * 4) * 128;
      bf16x8 af = *(const bf16x8*)(ab + kb4);
      bf16x8 bfr = *(const bf16x8*)(
          Wt + (size_t)(1 * 256 + fb0 + kt * 2 + h) * 512 + lane * 8);
      acc = __builtin_amdgcn_mfma_f32_16x16x32_bf16(af, bfr, acc, 0, 0, 0);
    }
  *(f32x4*)(X2B + (size_t)s * NCH + (size_t)ch2 * 16 + l4 * 4) = acc;
}

// -------------------------------------------------------------------------
// Fused pass A, plane-split: 1024 blocks. part 0 = c1 (planes 0,3),
// part 1 = c2 (planes 1,2,4; segment-entry x2 known from X2B -> emits FINAL
// A2,B2). Decode keeps each XCD on an 8-segment xb slice (2MB, L2-fit),
// with both parts co-resident. No LDS, no barriers.
// Summaries laid out [s][ch2(512)][b(16)] -> f32x4 wave-contiguous stores.
__global__ __launch_bounds__(256, 4) void fusedA_kernel(
    const u16* __restrict__ xb, const u16* __restrict__ Wt,
    const float* __restrict__ bias, const float* __restrict__ d_init,
    const float* __restrict__ X2B,
    float* __restrict__ A1, float* __restrict__ B1,
    float* __restrict__ A2, float* __restrict__ B2) {
  const int tid = threadIdx.x;
  const int lane = tid & 63;
  const int wc = tid >> 6;
  const int l15 = lane & 15, l4 = lane >> 4;
  const int bid = blockIdx.x;        // 0..1023
  const int xcd = bid & 7;           // HW: XCD = blockIdx % 8
  const int r2 = bid >> 3;           // 0..127
  const int part = r2 & 1;
  const int j = r2 >> 1;             // 0..63
  const int s = xcd * 8 + (j & 7);   // segment (XCD-grouped)
  const int bc = j >> 3;             // col-block 0..7
  const int dir = bc >> 2;
  const int ch2 = bc * 64 + wc * 16 + l15;
  const int fb0 = (bc * 4 + wc) * 8;
  const size_t lo = (size_t)(l4 * 128 + l15 * 8);
  const size_t oo = (size_t)s * NCH + (size_t)ch2 * 16 + l4 * 4;

  if (part == 0) {
    // ---- c1: planes 0 (x1), 3 (f1 logits) ----
    const float bv3 = bias[1536 + ch2];
    float a1[4] = {1.f, 1.f, 1.f, 1.f}, b1[4] = {0.f, 0.f, 0.f, 0.f};
    for (int rt = 0; rt < 8; ++rt) {
      int tf = s * 32 + rt * 4;
      int o0 = dir ? (SL - 1 - tf) : tf;
      int st = dir ? -1 : 1;
      const u16* ab[4];
#pragma unroll
      for (int i = 0; i < 4; ++i)
        ab[i] = xb + ((size_t)(o0 + i * st) << 12) + lo;
      f32x4 acc0[4], acc3[4];
#pragma unroll
      for (int i = 0; i < 4; ++i) {
        acc0[i] = (f32x4){0.f, 0.f, 0.f, 0.f};
        acc3[i] = (f32x4){0.f, 0.f, 0.f, 0.f};
      }
#pragma unroll
      for (int kt = 0; kt < 4; ++kt)
#pragma unroll
        for (int h = 0; h < 2; ++h) {
          const int kb4 = (kt * 8 + h * 4) * 128;
          const int fb = fb0 + kt * 2 + h;
          bf16x8 w0 = *(const bf16x8*)(Wt + (size_t)(fb) * 512 + lane * 8);
          bf16x8 w3 = *(const bf16x8*)(Wt + (size_t)(768 + fb) * 512 + lane * 8);
#pragma unroll
          for (int i = 0; i < 4; ++i) {
            bf16x8 af = *(const bf16x8*)(ab[i] + kb4);
            acc0[i] = __builtin_amdgcn_mfma_f32_16x16x32_bf16(af, w0, acc0[i], 0, 0, 0);
            acc3[i] = __builtin_amdgcn_mfma_f32_16x16x32_bf16(af, w3, acc3[i], 0, 0, 0);
          }
        }
#pragma unroll
      for (int i = 0; i < 4; ++i)
#pragma unroll
        for (int r = 0; r < 4; ++r) {
          float f1 = sigmoidf(acc3[i][r] + bv3);
          a1[r] *= f1;
          b1[r] = f1 * b1[r] + (1.f - f1) * acc0[i][r];
        }
    }
    *(f32x4*)(A1 + oo) = (f32x4){a1[0], a1[1], a1[2], a1[3]};
    *(f32x4*)(B1 + oo) = (f32x4){b1[0], b1[1], b1[2], b1[3]};
  } else {
    // ---- c2: planes 1 (x2), 2 (x3), 4 (f2 logits) ----
    const float bv4 = bias[2048 + ch2];
    const int chb = (l4 * 4) * 512 + ch2;
    float a2[4] = {1.f, 1.f, 1.f, 1.f}, b2[4] = {0.f, 0.f, 0.f, 0.f}, x2p[4];
    if (s == 0) {
#pragma unroll
      for (int r = 0; r < 4; ++r) x2p[r] = d_init[chb + r * 512];
    } else {
      f32x4 xv = *(const f32x4*)(X2B + oo - NCH);
#pragma unroll
      for (int r = 0; r < 4; ++r) x2p[r] = xv[r];
    }
    for (int rt = 0; rt < 8; ++rt) {
      int tf = s * 32 + rt * 4;
      int o0 = dir ? (SL - 1 - tf) : tf;
      int st = dir ? -1 : 1;
      const u16* ab[4];
#pragma unroll
      for (int i = 0; i < 4; ++i)
        ab[i] = xb + ((size_t)(o0 + i * st) << 12) + lo;
      f32x4 acc1[4], acc2[4], acc4[4];
#pragma unroll
      for (int i = 0; i < 4; ++i) {
        acc1[i] = (f32x4){0.f, 0.f, 0.f, 0.f};
        acc2[i] = (f32x4){0.f, 0.f, 0.f, 0.f};
        acc4[i] = (f32x4){0.f, 0.f, 0.f, 0.f};
      }
#pragma unroll
      for (int kt = 0; kt < 4; ++kt)
#pragma unroll
        for (int h = 0; h < 2; ++h) {
          const int kb4 = (kt * 8 + h * 4) * 128;
          const int fb = fb0 + kt * 2 + h;
          bf16x8 w1 = *(const bf16x8*)(Wt + (size_t)(256 + fb) * 512 + lane * 8);
          bf16x8 w2 = *(const bf16x8*)(Wt + (size_t)(512 + fb) * 512 + lane * 8);
          bf16x8 w4 = *(const bf16x8*)(Wt + (size_t)(1024 + fb) * 512 + lane * 8);
#pragma unroll
          for (int i = 0; i < 4; ++i) {
            bf16x8 af = *(const bf16x8*)(ab[i] + kb4);
            acc1[i] = __builtin_amdgcn_mfma_f32_16x16x32_bf16(af, w1, acc1[i], 0, 0, 0);
            acc2[i] = __builtin_amdgcn_mfma_f32_16x16x32_bf16(af, w2, acc2[i], 0, 0, 0);
            acc4[i] = __builtin_amdgcn_mfma_f32_16x16x32_bf16(af, w4, acc4[i], 0, 0, 0);
          }
        }
#pragma unroll
      for (int i = 0; i < 4; ++i)
#pragma unroll
        for (int r = 0; r < 4; ++r) {
          float f2 = sigmoidf(acc4[i][r] + bv4);
          float tmp = acc2[i][r] * x2p[r];
          a2[r] *= f2;
          b2[r] = f2 * b2[r] + (1.f - f2) * tmp;
          x2p[r] = acc1[i][r];
        }
    }
    *(f32x4*)(A2 + oo) = (f32x4){a2[0], a2[1], a2[2], a2[3]};
    *(f32x4*)(B2 + oo) = (f32x4){b2[0], b2[1], b2[2], b2[3]};
  }
}

// -------------------------------------------------------------------------
// Pass B: compose 64 segment maps per channel -> carry-in per segment.
// B2 is already final (X2B precomputed), so only 4 streamed arrays.
__global__ __launch_bounds__(256) void scanB_kernel(
    const float* __restrict__ A1, const float* __restrict__ B1,
    const float* __restrict__ A2, const float* __restrict__ B2,
    const float* __restrict__ X2B,
    const float* __restrict__ c1_init, const float* __restrict__ c2_init,
    float* __restrict__ C1c, float* __restrict__ C2c,
    float* __restrict__ out) {
  int t = blockIdx.x * 256 + threadIdx.x;  // < 8192, = ch2*16 + b
  int ch2 = t >> 4, b = t & 15;
  int ch = b * 512 + ch2;                  // real channel index
  float c1 = c1_init[ch], c2 = c2_init[ch];
#pragma unroll 8
  for (int s = 0; s < SEGS; ++s) {
    int o = s * NCH + t;
    C1c[o] = c1; C2c[o] = c2;
    c1 = A1[o] * c1 + B1[o];
    c2 = A2[o] * c2 + B2[o];
  }
  out[OFF_C1F + ch] = c1;
  out[OFF_C2F + ch] = c2;
  out[OFF_DF + ch] = X2B[(size_t)63 * NCH + t];  // x2 at flipped t=2047
}

// -------------------------------------------------------------------------
// Fused pass C, plane-split like fusedA: part 0 replays c1, part 1 replays
// c2; GEMM recompute + NT stores of f32 results straight to out
// (un-flip dir=1 on store).
__global__ __launch_bounds__(256, 4) void fusedC_kernel(
    const u16* __restrict__ xb, const u16* __restrict__ Wt,
    const float* __restrict__ bias, const float* __restrict__ d_init,
    const float* __restrict__ X2B,
    const float* __restrict__ C1c, const float* __restrict__ C2c,
    float* __restrict__ out) {
  const int tid = threadIdx.x;
  const int lane = tid & 63;
  const int wc = tid >> 6;
  const int l15 = lane & 15, l4 = lane >> 4;
  const int bid = blockIdx.x;
  const int xcd = bid & 7;
  const int r2 = bid >> 3;
  const int part = r2 & 1;
  const int j = r2 >> 1;
  const int s = xcd * 8 + (j & 7);
  const int bc = j >> 3;
  const int dir = bc >> 2;
  const int ch2 = bc * 64 + wc * 16 + l15;
  const int fb0 = (bc * 4 + wc) * 8;
  const size_t lo = (size_t)(l4 * 128 + l15 * 8);
  const size_t oo = (size_t)s * NCH + (size_t)ch2 * 16 + l4 * 4;
  const int chb = (l4 * 4) * 512 + ch2;

  if (part == 0) {
    // ---- c1 replay ----
    const float bv3 = bias[1536 + ch2];
    float c1[4];
    {
      f32x4 u0 = *(const f32x4*)(C1c + oo);
#pragma unroll
      for (int r = 0; r < 4; ++r) c1[r] = u0[r];
    }
    for (int rt = 0; rt < 8; ++rt) {
      int tf = s * 32 + rt * 4;
      int o0 = dir ? (SL - 1 - tf) : tf;
      int st = dir ? -1 : 1;
      const u16* ab[4];
#pragma unroll
      for (int i = 0; i < 4; ++i)
        ab[i] = xb + ((size_t)(o0 + i * st) << 12) + lo;
      f32x4 acc0[4], acc3[4];
#pragma unroll
      for (int i = 0; i < 4; ++i) {
        acc0[i] = (f32x4){0.f, 0.f, 0.f, 0.f};
        acc3[i] = (f32x4){0.f, 0.f, 0.f, 0.f};
      }
#pragma unroll
      for (int kt = 0; kt < 4; ++kt)
#pragma unroll
        for (int h = 0; h < 2; ++h) {
          const int kb4 = (kt * 8 + h * 4) * 128;
          const int fb = fb0 + kt * 2 + h;
          bf16x8 w0 = *(const bf16x8*)(Wt + (size_t)(fb) * 512 + lane * 8);
          bf16x8 w3 = *(const bf16x8*)(Wt + (size_t)(768 + fb) * 512 + lane * 8);
#pragma unroll
          for (int i = 0; i < 4; ++i) {
            bf16x8 af = *(const bf16x8*)(ab[i] + kb4);
            acc0[i] = __builtin_amdgcn_mfma_f32_16x16x32_bf16(af, w0, acc0[i], 0, 0, 0);
            acc3[i] = __builtin_amdgcn_mfma_f32_16x16x32_bf16(af, w3, acc3[i], 0, 0, 0);
          }
        }
#pragma unroll
      for (int i = 0; i < 4; ++i) {
        int tfl = s * 32 + rt * 4 + i;
        int t_out = dir ? (SL - 1 - tfl) : tfl;
        float* orow = out + (size_t)t_out * NCH + chb;
#pragma unroll
        for (int r = 0; r < 4; ++r) {
          float f1 = sigmoidf(acc3[i][r] + bv3);
          c1[r] = f1 * c1[r] + (1.f - f1) * acc0[i][r];
          __builtin_nontemporal_store(c1[r], orow + (size_t)r * 512);
        }
      }
    }
  } else {
    // ---- c2 replay ----
    const float bv4 = bias[2048 + ch2];
    float c2[4], x2p[4];
    {
      f32x4 w0 = *(const f32x4*)(C2c + oo);
#pragma unroll
      for (int r = 0; r < 4; ++r) c2[r] = w0[r];
      if (s == 0) {
#pragma unroll
        for (int r = 0; r < 4; ++r) x2p[r] = d_init[chb + r * 512];
      } else {
        f32x4 xv = *(const f32x4*)(X2B + oo - NCH);
#pragma unroll
        for (int r = 0; r < 4; ++r) x2p[r] = xv[r];
      }
    }
    for (int rt = 0; rt < 8; ++rt) {
      int tf = s * 32 + rt * 4;
      int o0 = dir ? (SL - 1 - tf) : tf;
      int st = dir ? -1 : 1;
      const u16* ab[4];
#pragma unroll
      for (int i = 0; i < 4; ++i)
        ab[i] = xb + ((size_t)(o0 + i * st) << 12) + lo;
      f32x4 acc1[4], acc2[4], acc4[4];
#pragma unroll
      for (int i = 0; i < 4; ++i) {
        acc1[i] = (f32x4){0.f, 0.f, 0.f, 0.f};
        acc2[i] = (f32x4){0.f, 0.f, 0.f, 0.f};
        acc4[i] = (f32x4){0.f, 0.f, 0.f, 0.f};
      }
#pragma unroll
      for (int kt = 0; kt < 4; ++kt)
#pragma unroll
        for (int h = 0; h < 2; ++h) {
          const int kb4 = (kt * 8 + h * 4) * 128;
          const int fb = fb0 + kt * 2 + h;
          bf16x8 w1 = *(const bf16x8*)(Wt + (size_t)(256 + fb) * 512 + lane * 8);
          bf16x8 w2 = *(const bf16x8*)(Wt + (size_t)(512 + fb) * 512 + lane * 8);
          bf16x8 w4 = *(const bf16x8*)(Wt + (size_t)(1024 + fb) * 512 + lane * 8);
#pragma unroll
          for (int i = 0; i < 4; ++i) {
            bf16x8 af = *(const bf16x8*)(ab[i] + kb4);
            acc1[i] = __builtin_amdgcn_mfma_f32_16x16x32_bf16(af, w1, acc1[i], 0, 0, 0);
            acc2[i] = __builtin_amdgcn_mfma_f32_16x16x32_bf16(af, w2, acc2[i], 0, 0, 0);
            acc4[i] = __builtin_amdgcn_mfma_f32_16x16x32_bf16(af, w4, acc4[i], 0, 0, 0);
          }
        }
#pragma unroll
      for (int i = 0; i < 4; ++i) {
        int tfl = s * 32 + rt * 4 + i;
        int t_out = dir ? (SL - 1 - tfl) : tfl;
        float* orow = out + (size_t)t_out * NCH + chb + OFF_C2S;
#pragma unroll
        for (int r = 0; r < 4; ++r) {
          float f2 = sigmoidf(acc4[i][r] + bv4);
          float tmp = acc2[i][r] * x2p[r];
          c2[r] = f2 * c2[r] + (1.f - f2) * tmp;
          x2p[r] = acc1[i][r];
          __builtin_nontemporal_store(c2[r], orow + (size_t)r * 512);
        }
      }
    }
  }
}

// -------------------------------------------------------------------------
extern "C" void kernel_launch(void* const* d_in, const int* in_sizes, int n_in,
                              void* d_out, int out_size, void* d_ws, size_t ws_size,
                              hipStream_t stream) {
  const float* x    = (const float*)d_in[0];   // (2048,16,256) f32
  const float* W    = (const float*)d_in[1];   // (256,3072) f32
  const float* bias = (const float*)d_in[2];   // (3072,) f32
  const float* c1i  = (const float*)d_in[3];   // (16,512) f32
  const float* c2i  = (const float*)d_in[4];
  const float* di   = (const float*)d_in[5];
  float* out = (float*)d_out;                  // f32 output

  uint8_t* w8 = (uint8_t*)d_ws;
  u16* Wt  = (u16*)w8;                         // 1,310,720 B
  u16* xb  = (u16*)(w8 + 1310720ull);          // 16,777,216 B
  float* X2B = (float*)(w8 + 18087936ull);     // 2,097,152 B
  float* A1  = (float*)(w8 + 20185088ull);     // 6 x 2,097,152 B
  float* B1  = A1  + SEGS * NCH;
  float* A2  = B1  + SEGS * NCH;
  float* B2  = A2  + SEGS * NCH;
  float* C1c = B2  + SEGS * NCH;
  float* C2c = C1c + SEGS * NCH;
  // total workspace use: ~32.8 MB

  hipLaunchKernelGGL(xconv_kernel, dim3(4096), dim3(256), 0, stream, x, xb);
  hipLaunchKernelGGL(repack_kernel, dim3(3072), dim3(256), 0, stream, W, Wt);
  hipLaunchKernelGGL(x2seg_kernel, dim3(64, 8), dim3(256), 0, stream,
                     xb, Wt, X2B);
  hipLaunchKernelGGL(fusedA_kernel, dim3(1024), dim3(256), 0, stream,
                     xb, Wt, bias, di, X2B, A1, B1, A2, B2);
  hipLaunchKernelGGL(scanB_kernel, dim3(32), dim3(256), 0, stream,
                     A1, B1, A2, B2, X2B, c1i, c2i, C1c, C2c, out);
  hipLaunchKernelGGL(fusedC_kernel, dim3(1024), dim3(256), 0, stream,
                     xb, Wt, bias, di, X2B, C1c, C2c, out);
}